// Round 9
// baseline (140.896 us; speedup 1.0000x reference)
//
#include <hip/hip_runtime.h>

// Problem constants
#define BB    8
#define DIMO  192
#define NH    3
#define HD    64
#define NK    3136   // keys per (b,h)
#define NQ    784    // queries per (b,h)
#define M1    25088  // B*H*W
#define M2    6272   // B*NQ
#define KSPLIT 4
#define KSLICE 784   // 12 full 64-key stages + one 16-key tail

#if __has_builtin(__builtin_amdgcn_mfma_f32_16x16x16bf16_1k)
#define HAVE_MFMA16 1
#else
#define HAVE_MFMA16 0
#endif

typedef __bf16 bf16x8 __attribute__((ext_vector_type(8)));
typedef float f32x4  __attribute__((ext_vector_type(4)));
typedef short s16x4  __attribute__((ext_vector_type(4)));

__device__ inline unsigned short f2bf(float f) {
    unsigned int u = __builtin_bit_cast(unsigned int, f);
    u += 0x7FFFu + ((u >> 16) & 1u);
    return (unsigned short)(u >> 16);
}

// ---------------------------------------------------------------------------
// Weight prep: blocks 0..17: W_qkv [96][576] -> Wb bf16 [576][96] (n-major);
// blocks 18..23: W_proj [192][192] -> Wpb bf16 [192n][192k].
// ---------------------------------------------------------------------------
__global__ void wprep(const float* __restrict__ Wqkv, const float* __restrict__ Wproj,
                      unsigned short* __restrict__ Wb, unsigned short* __restrict__ Wpb) {
    __shared__ float Ls[192][33];
    const int t = threadIdx.x;
    if (blockIdx.x < 18) {
        const int n0 = blockIdx.x * 32;
        int rr = t >> 5, c = t & 31;
#pragma unroll
        for (int rb = 0; rb < 12; ++rb) {
            int row = rb * 8 + rr;
            Ls[row][c] = Wqkv[(size_t)row * 576 + n0 + c];
        }
        __syncthreads();
        int n = t >> 3, kc = (t & 7) * 12;
#pragma unroll
        for (int j = 0; j < 12; j += 4) {
            ushort4 u = { f2bf(Ls[kc + j][n]), f2bf(Ls[kc + j + 1][n]),
                          f2bf(Ls[kc + j + 2][n]), f2bf(Ls[kc + j + 3][n]) };
            *(ushort4*)(Wb + (size_t)(n0 + n) * 96 + kc + j) = u;
        }
    } else {
        const int n0 = (blockIdx.x - 18) * 32;
        int rr = t >> 5, c = t & 31;
#pragma unroll
        for (int rb = 0; rb < 24; ++rb) {
            int row = rb * 8 + rr;
            Ls[row][c] = Wproj[(size_t)row * 192 + n0 + c];
        }
        __syncthreads();
        int n = t >> 3, kc = (t & 7) * 24;
#pragma unroll
        for (int j = 0; j < 24; j += 4) {
            ushort4 u = { f2bf(Ls[kc + j][n]), f2bf(Ls[kc + j + 1][n]),
                          f2bf(Ls[kc + j + 2][n]), f2bf(Ls[kc + j + 3][n]) };
            *(ushort4*)(Wpb + (size_t)(n0 + n) * 192 + kc + j) = u;
        }
    }
}

// ---------------------------------------------------------------------------
// Fused qkv GEMM + Q-maxpool. 616 blocks:
//   bid < 392: merged K+V block (x tile staged ONCE, two sequential epilogues)
//   bid >= 392: Q section, 112-row tile + fused 2x2 maxpool
// ---------------------------------------------------------------------------
__launch_bounds__(256)
__global__ void qkv_fused(const float* __restrict__ x,
                          const unsigned short* __restrict__ Wb,
                          const float* __restrict__ bias,
                          unsigned short* __restrict__ Qpb,
                          unsigned short* __restrict__ Kb,
                          unsigned short* __restrict__ Vt) {
    __shared__ __attribute__((aligned(16))) unsigned short xs[112 * 104]; // 208B rows
    const int tid = threadIdx.x;
    const int wave = tid >> 6, lane = tid & 63;
    const int quad = lane >> 4, l16 = lane & 15;
    const int bid = blockIdx.x;

    if (bid < 392) {
        const int m0 = bid * 64;
#pragma unroll
        for (int i = 0; i < 6; ++i) {
            int f = tid + i * 256;
            int r = f / 24, c4 = f % 24;
            float4 v = ((const float4*)x)[(size_t)(m0 + r) * 24 + c4];
            ushort4 u = { f2bf(v.x), f2bf(v.y), f2bf(v.z), f2bf(v.w) };
            *(ushort4*)&xs[r * 104 + c4 * 4] = u;
        }
        __syncthreads();

        const int mbase = m0 + wave * 16 + quad * 4;
        const int b = m0 / NK;
        const int key = mbase - b * NK;

#pragma unroll
        for (int sec = 1; sec <= 2; ++sec) {
            f32x4 acc[12];
#pragma unroll
            for (int i = 0; i < 12; ++i) acc[i] = (f32x4){0.f, 0.f, 0.f, 0.f};

            const unsigned short* wb = Wb + (size_t)(sec * 192 + l16) * 96 + quad * 8;
#pragma unroll
            for (int ch = 0; ch < 3; ++ch) {
                bf16x8 af = *(const bf16x8*)&xs[(wave * 16 + l16) * 104 + ch * 32 + quad * 8];
#pragma unroll
                for (int nf = 0; nf < 12; ++nf) {
                    bf16x8 bfr = *(const bf16x8*)(wb + (size_t)nf * 16 * 96 + ch * 32);
                    acc[nf] = __builtin_amdgcn_mfma_f32_16x16x32_bf16(af, bfr, acc[nf], 0, 0, 0);
                }
            }

            if (sec == 1) {
#pragma unroll
                for (int nf = 0; nf < 12; ++nf) {
                    int n = nf * 16 + l16;
                    float bs = bias[192 + n];
#pragma unroll
                    for (int i = 0; i < 4; ++i)
                        Kb[(size_t)(mbase + i) * 192 + n] = f2bf(acc[nf][i] + bs);
                }
            } else {
#pragma unroll
                for (int nf = 0; nf < 12; ++nf) {
                    int n = nf * 16 + l16;
                    float bs = bias[384 + n];
                    int hh = n >> 6, dd = n & 63;
                    ushort4 u = { f2bf(acc[nf][0] + bs), f2bf(acc[nf][1] + bs),
                                  f2bf(acc[nf][2] + bs), f2bf(acc[nf][3] + bs) };
                    *(ushort4*)(Vt + ((size_t)((b * 3 + hh) * 64 + dd)) * NK + key) = u;
                }
            }
        }
    } else {
        const int t = bid - 392;
        const int b = t / 28, hq = t % 28;
        const int m0 = b * NK + hq * 112;
#pragma unroll
        for (int i = 0; i < 11; ++i) {
            int f = tid + i * 256;
            if (f < 2688) {
                int r = f / 24, c4 = f % 24;
                float4 v = ((const float4*)x)[(size_t)(m0 + r) * 24 + c4];
                int rp = 2 * (r % 56) + (r / 56);   // row' = 2x + dy
                ushort4 u = { f2bf(v.x), f2bf(v.y), f2bf(v.z), f2bf(v.w) };
                *(ushort4*)&xs[rp * 104 + c4 * 4] = u;
            }
        }
        __syncthreads();

        f32x4 acc[7][3];
#pragma unroll
        for (int i = 0; i < 7; ++i)
#pragma unroll
            for (int j = 0; j < 3; ++j) acc[i][j] = (f32x4){0.f, 0.f, 0.f, 0.f};

        const unsigned short* wb = Wb + (size_t)(wave * 48 + l16) * 96 + quad * 8;
#pragma unroll
        for (int ch = 0; ch < 3; ++ch) {
            bf16x8 bfr[3];
#pragma unroll
            for (int jf = 0; jf < 3; ++jf)
                bfr[jf] = *(const bf16x8*)(wb + (size_t)jf * 16 * 96 + ch * 32);
#pragma unroll
            for (int mf = 0; mf < 7; ++mf) {
                bf16x8 a = *(const bf16x8*)&xs[(mf * 16 + l16) * 104 + ch * 32 + quad * 8];
#pragma unroll
                for (int jf = 0; jf < 3; ++jf)
                    acc[mf][jf] = __builtin_amdgcn_mfma_f32_16x16x32_bf16(a, bfr[jf], acc[mf][jf], 0, 0, 0);
            }
        }

#pragma unroll
        for (int mf = 0; mf < 7; ++mf) {
            int q = hq * 28 + mf * 4 + quad;
#pragma unroll
            for (int jf = 0; jf < 3; ++jf) {
                int n = wave * 48 + jf * 16 + l16;
                float m = fmaxf(fmaxf(acc[mf][jf][0], acc[mf][jf][1]),
                                fmaxf(acc[mf][jf][2], acc[mf][jf][3]));
                m = (m + bias[n]) * 0.125f;
                int hh = n >> 6, dd = n & 63;
                Qpb[((size_t)(b * 3 + hh) * NQ + q) * 64 + dd] = f2bf(m);
            }
        }
    }
}

// ---------------------------------------------------------------------------
// MFMA attention. Grid (13, 24, 4) = 1248 blocks; 4 waves x 16q each.
// KSLICE=784: 12 full 64-key stages + one 16-key tail (OOB staging reads land
// in adjacent workspace buffers; tail compute touches only valid keys).
// PV via K=16 MFMA (P stays in registers); fallback = P through LDS.
// ---------------------------------------------------------------------------
__launch_bounds__(256)
__global__ void attn_mfma(const unsigned short* __restrict__ Qpb,
                          const unsigned short* __restrict__ Kb,
                          const unsigned short* __restrict__ Vt,
                          float* __restrict__ Pnum,
                          float* __restrict__ Pden) {
    __shared__ __attribute__((aligned(16))) unsigned short Ks[64 * 88];  // [key][d]
    __shared__ __attribute__((aligned(16))) unsigned short Vs[64 * 88];  // [d][key]
#if !HAVE_MFMA16
    __shared__ __attribute__((aligned(16))) unsigned short Ps[4 * 16 * 72]; // 144B rows
#endif

    const int tid = threadIdx.x;
    const int wave = tid >> 6, lane = tid & 63;
    const int quad = lane >> 4, l16 = lane & 15;
    const int bh = blockIdx.y, b = bh / NH, h = bh % NH;
    const int qt = blockIdx.x * 64 + wave * 16;
    const int ks = blockIdx.z, k00 = ks * KSLICE;

    const int srow0 = tid >> 3, sch = (tid & 7) * 8;
    const unsigned short* kg  = Kb + ((size_t)(b * NK + k00) + srow0) * DIMO + h * 64 + sch;
    const unsigned short* kg1 = kg + (size_t)32 * DIMO;
    const unsigned short* vg  = Vt + ((size_t)bh * 64 + srow0) * NK + k00 + sch;
    const unsigned short* vg1 = vg + (size_t)32 * NK;

    uint4 kp0 = *(const uint4*)kg;
    uint4 kp1 = *(const uint4*)kg1;
    uint4 vp0 = *(const uint4*)vg;
    uint4 vp1 = *(const uint4*)vg1;

    // Q B-frags: lane holds q=l16, d=quad*8+j (+32*chunk)
    int qv = min(qt + l16, NQ - 1);
    const unsigned short* qp = Qpb + ((size_t)bh * NQ + qv) * HD + quad * 8;
    bf16x8 qf0 = *(const bf16x8*)qp;
    bf16x8 qf1 = *(const bf16x8*)(qp + 32);

    f32x4 on[4];
#pragma unroll
    for (int i = 0; i < 4; ++i) on[i] = (f32x4){0.f, 0.f, 0.f, 0.f};
    float dden = 0.f;

#if !HAVE_MFMA16
    unsigned short* myP = Ps + wave * 16 * 72;
#endif

    for (int s = 0; s < 13; ++s) {
        __syncthreads();
        *(uint4*)&Ks[srow0 * 88 + sch]        = kp0;
        *(uint4*)&Ks[(srow0 + 32) * 88 + sch] = kp1;
        *(uint4*)&Vs[srow0 * 88 + sch]        = vp0;
        *(uint4*)&Vs[(srow0 + 32) * 88 + sch] = vp1;
        __syncthreads();
        if (s < 12) {
            kp0 = *(const uint4*)(kg  + (size_t)(s + 1) * 64 * DIMO);
            kp1 = *(const uint4*)(kg1 + (size_t)(s + 1) * 64 * DIMO);
            vp0 = *(const uint4*)(vg  + (s + 1) * 64);
            vp1 = *(const uint4*)(vg1 + (s + 1) * 64);
        }

        const int ng = (s == 12) ? 1 : 4;   // tail stage: 16 keys
        for (int g = 0; g < ng; ++g) {
            const int krow = (g * 16 + l16) * 88;
            bf16x8 kf0 = *(const bf16x8*)&Ks[krow + quad * 8];
            bf16x8 kf1 = *(const bf16x8*)&Ks[krow + 32 + quad * 8];
            f32x4 sa = (f32x4){0.f, 0.f, 0.f, 0.f};
            sa = __builtin_amdgcn_mfma_f32_16x16x32_bf16(kf0, qf0, sa, 0, 0, 0);
            sa = __builtin_amdgcn_mfma_f32_16x16x32_bf16(kf1, qf1, sa, 0, 0, 0);
            float p0 = __expf(sa[0]), p1 = __expf(sa[1]);
            float p2 = __expf(sa[2]), p3 = __expf(sa[3]);
            dden += (p0 + p1) + (p2 + p3);
#if HAVE_MFMA16
            s16x4 pb = { (short)f2bf(p0), (short)f2bf(p1),
                         (short)f2bf(p2), (short)f2bf(p3) };
#pragma unroll
            for (int dsub = 0; dsub < 4; ++dsub) {
                s16x4 vf = *(const s16x4*)&Vs[(dsub * 16 + l16) * 88 + g * 16 + quad * 4];
                on[dsub] = __builtin_amdgcn_mfma_f32_16x16x16bf16_1k(vf, pb, on[dsub], 0, 0, 0);
            }
#else
            ushort4 pw = { f2bf(p0), f2bf(p1), f2bf(p2), f2bf(p3) };
            *(ushort4*)&myP[l16 * 72 + g * 16 + quad * 4] = pw;
#endif
        }
#if !HAVE_MFMA16
        if (s == 12) {   // zero the dead half of the 0..31 key range
            ushort4 z = { 0, 0, 0, 0 };
            *(ushort4*)&myP[l16 * 72 + 16 + quad * 4] = z;
        }
        const int nhalf = (s == 12) ? 1 : 2;
        for (int half = 0; half < nhalf; ++half) {
            bf16x8 pf = *(const bf16x8*)&myP[l16 * 72 + half * 32 + quad * 8];
#pragma unroll
            for (int dsub = 0; dsub < 4; ++dsub) {
                bf16x8 vf = *(const bf16x8*)&Vs[(dsub * 16 + l16) * 88 + half * 32 + quad * 8];
                on[dsub] = __builtin_amdgcn_mfma_f32_16x16x32_bf16(vf, pf, on[dsub], 0, 0, 0);
            }
        }
#endif
    }

    dden += __shfl_xor(dden, 16, 64);
    dden += __shfl_xor(dden, 32, 64);
    int q = qt + l16;
    if (q < NQ) {
        size_t base = (size_t)ks * (24 * NQ * HD) + ((size_t)bh * NQ + q) * HD + quad * 4;
#pragma unroll
        for (int dsub = 0; dsub < 4; ++dsub)
            *(f32x4*)(Pnum + base + dsub * 16) = on[dsub];
        if (quad == 0) Pden[ks * (24 * NQ) + bh * NQ + q] = dden;
    }
}

// ---------------------------------------------------------------------------
// Fused combine + proj. Grid 392 blocks; block = 16x192 output tile.
// ---------------------------------------------------------------------------
__launch_bounds__(256)
__global__ void proj_comb(const float* __restrict__ Pnum,
                          const float* __restrict__ Pden,
                          const unsigned short* __restrict__ Wpb,
                          const float* __restrict__ bproj,
                          float* __restrict__ out) {
    __shared__ __attribute__((aligned(16))) unsigned short as_[16 * 200]; // 400B rows
    __shared__ float rden[16][4];
    const int tid = threadIdx.x;
    const int wave = tid >> 6, lane = tid & 63;
    const int quad = lane >> 4, l16 = lane & 15;
    const int m0 = blockIdx.x * 16;

    if (tid < 48) {
        int r = tid / 3, h = tid % 3;
        int gq = m0 + r, b = gq / NQ, qq = gq - b * NQ;
        float den = 0.f;
#pragma unroll
        for (int s = 0; s < KSPLIT; ++s)
            den += Pden[s * (24 * NQ) + (b * 3 + h) * NQ + qq];
        rden[r][h] = 1.0f / den;
    }
    __syncthreads();

    {
        int r = tid >> 4, cl = tid & 15;
        int gq = m0 + r, b = gq / NQ, qq = gq - b * NQ;
#pragma unroll
        for (int i = 0; i < 3; ++i) {
            int c = cl + i * 16;           // 0..47 (f32x4 chunks of the 192 cols)
            int h = c >> 4, d = (c & 15) * 4;
            const float* p = Pnum + ((size_t)(b * 3 + h) * NQ + qq) * 64 + d;
            f32x4 num = (f32x4){0.f, 0.f, 0.f, 0.f};
#pragma unroll
            for (int s = 0; s < KSPLIT; ++s)
                num = num + *(const f32x4*)(p + (size_t)s * (24 * NQ * HD));
            float rc = rden[r][h];
            ushort4 u = { f2bf(num[0] * rc), f2bf(num[1] * rc),
                          f2bf(num[2] * rc), f2bf(num[3] * rc) };
            *(ushort4*)&as_[r * 200 + c * 4] = u;
        }
    }
    __syncthreads();

    f32x4 acc[3];
#pragma unroll
    for (int j = 0; j < 3; ++j) acc[j] = (f32x4){0.f, 0.f, 0.f, 0.f};

    const unsigned short* wp = Wpb + (size_t)(wave * 48 + l16) * 192 + quad * 8;
#pragma unroll
    for (int ch = 0; ch < 6; ++ch) {
        bf16x8 a = *(const bf16x8*)&as_[l16 * 200 + ch * 32 + quad * 8];
#pragma unroll
        for (int jf = 0; jf < 3; ++jf) {
            bf16x8 bfr = *(const bf16x8*)(wp + (size_t)jf * 16 * 192 + ch * 32);
            acc[jf] = __builtin_amdgcn_mfma_f32_16x16x32_bf16(a, bfr, acc[jf], 0, 0, 0);
        }
    }

    const int m = m0 + quad * 4;
#pragma unroll
    for (int jf = 0; jf < 3; ++jf) {
        int n = wave * 48 + jf * 16 + l16;
        float bs = bproj[n];
#pragma unroll
        for (int i = 0; i < 4; ++i)
            out[(size_t)(m + i) * 192 + n] = acc[jf][i] + bs;
    }
}

// ---------------------------------------------------------------------------
extern "C" void kernel_launch(void* const* d_in, const int* in_sizes, int n_in,
                              void* d_out, int out_size, void* d_ws, size_t ws_size,
                              hipStream_t stream) {
    const float* x     = (const float*)d_in[0];
    const float* Wqkv  = (const float*)d_in[1];
    const float* bqkv  = (const float*)d_in[2];
    const float* Wproj = (const float*)d_in[3];
    const float* bproj = (const float*)d_in[4];
    float* out = (float*)d_out;

    // Workspace (~41 MB). NOTE: attn's 16-key tail stage over-reads Kb into
    // Vt and Vt into Wb (staged but never used in compute) — keep this order.
    float* Pnum = (float*)d_ws;                              // 4*24*784*64 f
    float* Pden = Pnum + (size_t)KSPLIT * 24 * NQ * HD;      // 4*24*784 f
    unsigned short* Qpb = (unsigned short*)(Pden + (size_t)KSPLIT * 24 * NQ); // 1,204,224 us
    unsigned short* Kb  = Qpb + (size_t)24 * NQ * HD;        // 4,816,896 us
    unsigned short* Vt  = Kb + (size_t)BB * NK * DIMO;       // 4,816,896 us
    unsigned short* Wb  = Vt + (size_t)24 * HD * NK;         // 55,296 us
    unsigned short* Wpb = Wb + (size_t)576 * 96;             // 36,864 us

    // 1) weight prep
    wprep<<<24, 256, 0, stream>>>(Wqkv, Wproj, Wb, Wpb);

    // 2) fused qkv GEMM + Q-maxpool (KV merged: 392 + Q: 224 blocks)
    qkv_fused<<<616, 256, 0, stream>>>(x, Wb, bqkv, Qpb, Kb, Vt);

    // 3) MFMA attention partials
    attn_mfma<<<dim3(13, 24, KSPLIT), 256, 0, stream>>>(Qpb, Kb, Vt, Pnum, Pden);

    // 4) fused combine + proj
    proj_comb<<<392, 256, 0, stream>>>(Pnum, Pden, Wpb, bproj, out);
}

// Round 10
// 138.395 us; speedup vs baseline: 1.0181x; 1.0181x over previous
//
#include <hip/hip_runtime.h>

// Problem constants
#define BB    8
#define DIMO  192
#define NH    3
#define HD    64
#define NK    3136   // keys per (b,h)
#define NQ    784    // queries per (b,h)
#define M1    25088  // B*H*W
#define M2    6272   // B*NQ
#define KSPLIT 7
#define KSLICE 448   // 7 stages of 64 keys (exact, no tail)
#define PSTR  56     // P-tile row stride (ushorts): 112 B = 7*16, b128-aligned

// Q pre-scale: 1/sqrt(64) * log2(e)  -> exp(S) computed as exp2(S')
#define QSCALE 0.18033688011112042f

#if __has_builtin(__builtin_amdgcn_mfma_f32_16x16x16bf16_1k)
#define HAVE_MFMA16 1
#else
#define HAVE_MFMA16 0
#endif

#if __has_builtin(__builtin_amdgcn_exp2f)
#define FEXP2(x) __builtin_amdgcn_exp2f(x)
#else
#define FEXP2(x) exp2f(x)
#endif

typedef __bf16 bf16x8 __attribute__((ext_vector_type(8)));
typedef float f32x4  __attribute__((ext_vector_type(4)));
typedef short s16x4  __attribute__((ext_vector_type(4)));

__device__ inline unsigned short f2bf(float f) {
    unsigned int u = __builtin_bit_cast(unsigned int, f);
    u += 0x7FFFu + ((u >> 16) & 1u);
    return (unsigned short)(u >> 16);
}

// pack bf16(a) (low) | bf16(b) (high), round-half-up: 2 adds + 1 v_perm
__device__ inline unsigned int pk_bf16(float a, float b) {
    unsigned int ua = __builtin_bit_cast(unsigned int, a) + 0x8000u;
    unsigned int ub = __builtin_bit_cast(unsigned int, b) + 0x8000u;
    return __builtin_amdgcn_perm(ub, ua, 0x07060302u);
}

// ---------------------------------------------------------------------------
// Weight prep: blocks 0..17: W_qkv -> Wb bf16 [576][96]; 18..23: W_proj ->
// Wpb bf16 [192n][192k].
// ---------------------------------------------------------------------------
__global__ void wprep(const float* __restrict__ Wqkv, const float* __restrict__ Wproj,
                      unsigned short* __restrict__ Wb, unsigned short* __restrict__ Wpb) {
    __shared__ float Ls[192][33];
    const int t = threadIdx.x;
    if (blockIdx.x < 18) {
        const int n0 = blockIdx.x * 32;
        int rr = t >> 5, c = t & 31;
#pragma unroll
        for (int rb = 0; rb < 12; ++rb) {
            int row = rb * 8 + rr;
            Ls[row][c] = Wqkv[(size_t)row * 576 + n0 + c];
        }
        __syncthreads();
        int n = t >> 3, kc = (t & 7) * 12;
#pragma unroll
        for (int j = 0; j < 12; j += 4) {
            ushort4 u = { f2bf(Ls[kc + j][n]), f2bf(Ls[kc + j + 1][n]),
                          f2bf(Ls[kc + j + 2][n]), f2bf(Ls[kc + j + 3][n]) };
            *(ushort4*)(Wb + (size_t)(n0 + n) * 96 + kc + j) = u;
        }
    } else {
        const int n0 = (blockIdx.x - 18) * 32;
        int rr = t >> 5, c = t & 31;
#pragma unroll
        for (int rb = 0; rb < 24; ++rb) {
            int row = rb * 8 + rr;
            Ls[row][c] = Wproj[(size_t)row * 192 + n0 + c];
        }
        __syncthreads();
        int n = t >> 3, kc = (t & 7) * 24;
#pragma unroll
        for (int j = 0; j < 24; j += 4) {
            ushort4 u = { f2bf(Ls[kc + j][n]), f2bf(Ls[kc + j + 1][n]),
                          f2bf(Ls[kc + j + 2][n]), f2bf(Ls[kc + j + 3][n]) };
            *(ushort4*)(Wpb + (size_t)(n0 + n) * 192 + kc + j) = u;
        }
    }
}

// ---------------------------------------------------------------------------
// Fused qkv GEMM + Q-maxpool. 616 blocks: bid<392 merged K+V (x staged once);
// bid>=392 Q section (112-row tile, pool-permuted rows). Q scaled by QSCALE.
// ---------------------------------------------------------------------------
__launch_bounds__(256)
__global__ void qkv_fused(const float* __restrict__ x,
                          const unsigned short* __restrict__ Wb,
                          const float* __restrict__ bias,
                          unsigned short* __restrict__ Qpb,
                          unsigned short* __restrict__ Kb,
                          unsigned short* __restrict__ Vt) {
    __shared__ __attribute__((aligned(16))) unsigned short xs[112 * 104]; // 208B rows
    const int tid = threadIdx.x;
    const int wave = tid >> 6, lane = tid & 63;
    const int quad = lane >> 4, l16 = lane & 15;
    const int bid = blockIdx.x;

    if (bid < 392) {
        const int m0 = bid * 64;
#pragma unroll
        for (int i = 0; i < 6; ++i) {
            int f = tid + i * 256;
            int r = f / 24, c4 = f % 24;
            float4 v = ((const float4*)x)[(size_t)(m0 + r) * 24 + c4];
            ushort4 u = { f2bf(v.x), f2bf(v.y), f2bf(v.z), f2bf(v.w) };
            *(ushort4*)&xs[r * 104 + c4 * 4] = u;
        }
        __syncthreads();

        const int mbase = m0 + wave * 16 + quad * 4;
        const int b = m0 / NK;
        const int key = mbase - b * NK;

#pragma unroll
        for (int sec = 1; sec <= 2; ++sec) {
            f32x4 acc[12];
#pragma unroll
            for (int i = 0; i < 12; ++i) acc[i] = (f32x4){0.f, 0.f, 0.f, 0.f};

            const unsigned short* wb = Wb + (size_t)(sec * 192 + l16) * 96 + quad * 8;
#pragma unroll
            for (int ch = 0; ch < 3; ++ch) {
                bf16x8 af = *(const bf16x8*)&xs[(wave * 16 + l16) * 104 + ch * 32 + quad * 8];
#pragma unroll
                for (int nf = 0; nf < 12; ++nf) {
                    bf16x8 bfr = *(const bf16x8*)(wb + (size_t)nf * 16 * 96 + ch * 32);
                    acc[nf] = __builtin_amdgcn_mfma_f32_16x16x32_bf16(af, bfr, acc[nf], 0, 0, 0);
                }
            }

            if (sec == 1) {
#pragma unroll
                for (int nf = 0; nf < 12; ++nf) {
                    int n = nf * 16 + l16;
                    float bs = bias[192 + n];
#pragma unroll
                    for (int i = 0; i < 4; ++i)
                        Kb[(size_t)(mbase + i) * 192 + n] = f2bf(acc[nf][i] + bs);
                }
            } else {
#pragma unroll
                for (int nf = 0; nf < 12; ++nf) {
                    int n = nf * 16 + l16;
                    float bs = bias[384 + n];
                    int hh = n >> 6, dd = n & 63;
                    ushort4 u = { f2bf(acc[nf][0] + bs), f2bf(acc[nf][1] + bs),
                                  f2bf(acc[nf][2] + bs), f2bf(acc[nf][3] + bs) };
                    *(ushort4*)(Vt + ((size_t)((b * 3 + hh) * 64 + dd)) * NK + key) = u;
                }
            }
        }
    } else {
        const int t = bid - 392;
        const int b = t / 28, hq = t % 28;
        const int m0 = b * NK + hq * 112;
#pragma unroll
        for (int i = 0; i < 11; ++i) {
            int f = tid + i * 256;
            if (f < 2688) {
                int r = f / 24, c4 = f % 24;
                float4 v = ((const float4*)x)[(size_t)(m0 + r) * 24 + c4];
                int rp = 2 * (r % 56) + (r / 56);   // row' = 2x + dy
                ushort4 u = { f2bf(v.x), f2bf(v.y), f2bf(v.z), f2bf(v.w) };
                *(ushort4*)&xs[rp * 104 + c4 * 4] = u;
            }
        }
        __syncthreads();

        f32x4 acc[7][3];
#pragma unroll
        for (int i = 0; i < 7; ++i)
#pragma unroll
            for (int j = 0; j < 3; ++j) acc[i][j] = (f32x4){0.f, 0.f, 0.f, 0.f};

        const unsigned short* wb = Wb + (size_t)(wave * 48 + l16) * 96 + quad * 8;
#pragma unroll
        for (int ch = 0; ch < 3; ++ch) {
            bf16x8 bfr[3];
#pragma unroll
            for (int jf = 0; jf < 3; ++jf)
                bfr[jf] = *(const bf16x8*)(wb + (size_t)jf * 16 * 96 + ch * 32);
#pragma unroll
            for (int mf = 0; mf < 7; ++mf) {
                bf16x8 a = *(const bf16x8*)&xs[(mf * 16 + l16) * 104 + ch * 32 + quad * 8];
#pragma unroll
                for (int jf = 0; jf < 3; ++jf)
                    acc[mf][jf] = __builtin_amdgcn_mfma_f32_16x16x32_bf16(a, bfr[jf], acc[mf][jf], 0, 0, 0);
            }
        }

#pragma unroll
        for (int mf = 0; mf < 7; ++mf) {
            int q = hq * 28 + mf * 4 + quad;
#pragma unroll
            for (int jf = 0; jf < 3; ++jf) {
                int n = wave * 48 + jf * 16 + l16;
                float m = fmaxf(fmaxf(acc[mf][jf][0], acc[mf][jf][1]),
                                fmaxf(acc[mf][jf][2], acc[mf][jf][3]));
                m = (m + bias[n]) * QSCALE;
                int hh = n >> 6, dd = n & 63;
                Qpb[((size_t)(b * 3 + hh) * NQ + q) * 64 + dd] = f2bf(m);
            }
        }
    }
}

// ---------------------------------------------------------------------------
// MFMA attention. Grid (7,24,7) = 1176 blocks, 4 waves x 32q (R8 geometry —
// K/V fragments shared across the 2 qsubs). P = exp2(S') via single v_exp;
// bf16 pack via v_perm round-half-up; den via ones-MFMA (no VALU adds).
// ---------------------------------------------------------------------------
__launch_bounds__(256)
__global__ void attn_mfma(const unsigned short* __restrict__ Qpb,
                          const unsigned short* __restrict__ Kb,
                          const unsigned short* __restrict__ Vt,
                          float* __restrict__ Pnum,
                          float* __restrict__ Pden) {
    __shared__ __attribute__((aligned(16))) unsigned short Ks[64 * 88];  // [key][d]
    __shared__ __attribute__((aligned(16))) unsigned short Vs[64 * 88];  // [d][key]
#if !HAVE_MFMA16
    __shared__ __attribute__((aligned(16))) unsigned short Ps[4 * 32 * PSTR];
#endif

    const int tid = threadIdx.x;
    const int wave = tid >> 6, lane = tid & 63;
    const int quad = lane >> 4, l16 = lane & 15;
    const int bh = blockIdx.y, b = bh / NH, h = bh % NH;
    const int qt = blockIdx.x * 128 + wave * 32;
    const int ks = blockIdx.z, k00 = ks * KSLICE;

    const int srow0 = tid >> 3, sch = (tid & 7) * 8;
    const unsigned short* kg  = Kb + ((size_t)(b * NK + k00) + srow0) * DIMO + h * 64 + sch;
    const unsigned short* kg1 = kg + (size_t)32 * DIMO;
    const unsigned short* vg  = Vt + ((size_t)bh * 64 + srow0) * NK + k00 + sch;
    const unsigned short* vg1 = vg + (size_t)32 * NK;

    uint4 kp0 = *(const uint4*)kg;
    uint4 kp1 = *(const uint4*)kg1;
    uint4 vp0 = *(const uint4*)vg;
    uint4 vp1 = *(const uint4*)vg1;

    // Q B-frags: lane holds q=l16 (+16*qsub), d=quad*8+j (+32*chunk)
    int qa = min(qt + l16, NQ - 1);
    int qb = min(qt + 16 + l16, NQ - 1);
    const unsigned short* qpa = Qpb + ((size_t)bh * NQ + qa) * HD + quad * 8;
    const unsigned short* qpc = Qpb + ((size_t)bh * NQ + qb) * HD + quad * 8;
    bf16x8 qf[2][2];
    qf[0][0] = *(const bf16x8*)qpa;  qf[0][1] = *(const bf16x8*)(qpa + 32);
    qf[1][0] = *(const bf16x8*)qpc;  qf[1][1] = *(const bf16x8*)(qpc + 32);

    f32x4 on[4][2];
#pragma unroll
    for (int i = 0; i < 4; ++i)
#pragma unroll
        for (int j = 0; j < 2; ++j) on[i][j] = (f32x4){0.f, 0.f, 0.f, 0.f};
    f32x4 dn[2];
    dn[0] = (f32x4){0.f, 0.f, 0.f, 0.f};
    dn[1] = (f32x4){0.f, 0.f, 0.f, 0.f};

#if HAVE_MFMA16
    const short one16 = (short)0x3F80;           // bf16 1.0
    s16x4 ones4 = { one16, one16, one16, one16 };
#else
    const __bf16 one = (__bf16)1.0f;
    bf16x8 ones8 = { one, one, one, one, one, one, one, one };
    unsigned short* myP = Ps + wave * 32 * PSTR;
#endif

    for (int s = 0; s < 7; ++s) {
        __syncthreads();
        *(uint4*)&Ks[srow0 * 88 + sch]        = kp0;
        *(uint4*)&Ks[(srow0 + 32) * 88 + sch] = kp1;
        *(uint4*)&Vs[srow0 * 88 + sch]        = vp0;
        *(uint4*)&Vs[(srow0 + 32) * 88 + sch] = vp1;
        __syncthreads();
        if (s < 6) {
            kp0 = *(const uint4*)(kg  + (size_t)(s + 1) * 64 * DIMO);
            kp1 = *(const uint4*)(kg1 + (size_t)(s + 1) * 64 * DIMO);
            vp0 = *(const uint4*)(vg  + (s + 1) * 64);
            vp1 = *(const uint4*)(vg1 + (s + 1) * 64);
        }

#if HAVE_MFMA16
#pragma unroll
        for (int g = 0; g < 4; ++g) {
            const int krow = (g * 16 + l16) * 88;
            bf16x8 kf0 = *(const bf16x8*)&Ks[krow + quad * 8];
            bf16x8 kf1 = *(const bf16x8*)&Ks[krow + 32 + quad * 8];
            s16x4 vf[4];
#pragma unroll
            for (int dsub = 0; dsub < 4; ++dsub)
                vf[dsub] = *(const s16x4*)&Vs[(dsub * 16 + l16) * 88 + g * 16 + quad * 4];
#pragma unroll
            for (int qsub = 0; qsub < 2; ++qsub) {
                f32x4 sa = (f32x4){0.f, 0.f, 0.f, 0.f};
                sa = __builtin_amdgcn_mfma_f32_16x16x32_bf16(kf0, qf[qsub][0], sa, 0, 0, 0);
                sa = __builtin_amdgcn_mfma_f32_16x16x32_bf16(kf1, qf[qsub][1], sa, 0, 0, 0);
                float p0 = FEXP2(sa[0]), p1 = FEXP2(sa[1]);
                float p2 = FEXP2(sa[2]), p3 = FEXP2(sa[3]);
                uint2 pk = { pk_bf16(p0, p1), pk_bf16(p2, p3) };
                s16x4 pb = __builtin_bit_cast(s16x4, pk);
                dn[qsub] = __builtin_amdgcn_mfma_f32_16x16x16bf16_1k(ones4, pb, dn[qsub], 0, 0, 0);
#pragma unroll
                for (int dsub = 0; dsub < 4; ++dsub)
                    on[dsub][qsub] = __builtin_amdgcn_mfma_f32_16x16x16bf16_1k(
                        vf[dsub], pb, on[dsub][qsub], 0, 0, 0);
            }
        }
#else
#pragma unroll
        for (int half = 0; half < 2; ++half) {
#pragma unroll
            for (int ksub = 0; ksub < 2; ++ksub) {
                const int krow = (half * 32 + ksub * 16 + l16) * 88;
                bf16x8 kf0 = *(const bf16x8*)&Ks[krow + quad * 8];
                bf16x8 kf1 = *(const bf16x8*)&Ks[krow + 32 + quad * 8];
#pragma unroll
                for (int qsub = 0; qsub < 2; ++qsub) {
                    f32x4 sa = (f32x4){0.f, 0.f, 0.f, 0.f};
                    sa = __builtin_amdgcn_mfma_f32_16x16x32_bf16(kf0, qf[qsub][0], sa, 0, 0, 0);
                    sa = __builtin_amdgcn_mfma_f32_16x16x32_bf16(kf1, qf[qsub][1], sa, 0, 0, 0);
                    float p0 = FEXP2(sa[0]), p1 = FEXP2(sa[1]);
                    float p2 = FEXP2(sa[2]), p3 = FEXP2(sa[3]);
                    uint2 pk = { pk_bf16(p0, p1), pk_bf16(p2, p3) };
                    *(uint2*)&myP[(qsub * 16 + l16) * PSTR + ksub * 16 + quad * 4] = pk;
                }
            }
            bf16x8 pf0 = *(const bf16x8*)&myP[l16 * PSTR + quad * 8];
            bf16x8 pf1 = *(const bf16x8*)&myP[(16 + l16) * PSTR + quad * 8];
            dn[0] = __builtin_amdgcn_mfma_f32_16x16x32_bf16(ones8, pf0, dn[0], 0, 0, 0);
            dn[1] = __builtin_amdgcn_mfma_f32_16x16x32_bf16(ones8, pf1, dn[1], 0, 0, 0);
#pragma unroll
            for (int dsub = 0; dsub < 4; ++dsub) {
                bf16x8 vf = *(const bf16x8*)&Vs[(dsub * 16 + l16) * 88 + half * 32 + quad * 8];
                on[dsub][0] = __builtin_amdgcn_mfma_f32_16x16x32_bf16(vf, pf0, on[dsub][0], 0, 0, 0);
                on[dsub][1] = __builtin_amdgcn_mfma_f32_16x16x32_bf16(vf, pf1, on[dsub][1], 0, 0, 0);
            }
        }
#endif
    }

#pragma unroll
    for (int qsub = 0; qsub < 2; ++qsub) {
        int q = qt + qsub * 16 + l16;
        if (q < NQ) {
            size_t base = (size_t)ks * (24 * NQ * HD) + ((size_t)bh * NQ + q) * HD + quad * 4;
#pragma unroll
            for (int dsub = 0; dsub < 4; ++dsub)
                *(f32x4*)(Pnum + base + dsub * 16) = on[dsub][qsub];
            if (quad == 0) Pden[ks * (24 * NQ) + bh * NQ + q] = dn[qsub][0];
        }
    }
}

// ---------------------------------------------------------------------------
// Fused combine + proj. Grid 392 blocks; block = 16x192 output tile.
// ---------------------------------------------------------------------------
__launch_bounds__(256)
__global__ void proj_comb(const float* __restrict__ Pnum,
                          const float* __restrict__ Pden,
                          const unsigned short* __restrict__ Wpb,
                          const float* __restrict__ bproj,
                          float* __restrict__ out) {
    __shared__ __attribute__((aligned(16))) unsigned short as_[16 * 200]; // 400B rows
    __shared__ float rden[16][4];
    const int tid = threadIdx.x;
    const int wave = tid >> 6, lane = tid & 63;
    const int quad = lane >> 4, l16 = lane & 15;
    const int m0 = blockIdx.x * 16;

    if (tid < 48) {
        int r = tid / 3, h = tid % 3;
        int gq = m0 + r, b = gq / NQ, qq = gq - b * NQ;
        float den = 0.f;
#pragma unroll
        for (int s = 0; s < KSPLIT; ++s)
            den += Pden[s * (24 * NQ) + (b * 3 + h) * NQ + qq];
        rden[r][h] = 1.0f / den;
    }
    __syncthreads();

    {
        int r = tid >> 4, cl = tid & 15;
        int gq = m0 + r, b = gq / NQ, qq = gq - b * NQ;
#pragma unroll
        for (int i = 0; i < 3; ++i) {
            int c = cl + i * 16;           // 0..47 (f32x4 chunks of the 192 cols)
            int h = c >> 4, d = (c & 15) * 4;
            const float* p = Pnum + ((size_t)(b * 3 + h) * NQ + qq) * 64 + d;
            f32x4 num = (f32x4){0.f, 0.f, 0.f, 0.f};
#pragma unroll
            for (int s = 0; s < KSPLIT; ++s)
                num = num + *(const f32x4*)(p + (size_t)s * (24 * NQ * HD));
            float rc = rden[r][h];
            ushort4 u = { f2bf(num[0] * rc), f2bf(num[1] * rc),
                          f2bf(num[2] * rc), f2bf(num[3] * rc) };
            *(ushort4*)&as_[r * 200 + c * 4] = u;
        }
    }
    __syncthreads();

    f32x4 acc[3];
#pragma unroll
    for (int j = 0; j < 3; ++j) acc[j] = (f32x4){0.f, 0.f, 0.f, 0.f};

    const unsigned short* wp = Wpb + (size_t)(wave * 48 + l16) * 192 + quad * 8;
#pragma unroll
    for (int ch = 0; ch < 6; ++ch) {
        bf16x8 a = *(const bf16x8*)&as_[l16 * 200 + ch * 32 + quad * 8];
#pragma unroll
        for (int jf = 0; jf < 3; ++jf) {
            bf16x8 bfr = *(const bf16x8*)(wp + (size_t)jf * 16 * 192 + ch * 32);
            acc[jf] = __builtin_amdgcn_mfma_f32_16x16x32_bf16(a, bfr, acc[jf], 0, 0, 0);
        }
    }

    const int m = m0 + quad * 4;
#pragma unroll
    for (int jf = 0; jf < 3; ++jf) {
        int n = wave * 48 + jf * 16 + l16;
        float bs = bproj[n];
#pragma unroll
        for (int i = 0; i < 4; ++i)
            out[(size_t)(m + i) * 192 + n] = acc[jf][i] + bs;
    }
}

// ---------------------------------------------------------------------------
extern "C" void kernel_launch(void* const* d_in, const int* in_sizes, int n_in,
                              void* d_out, int out_size, void* d_ws, size_t ws_size,
                              hipStream_t stream) {
    const float* x     = (const float*)d_in[0];
    const float* Wqkv  = (const float*)d_in[1];
    const float* bqkv  = (const float*)d_in[2];
    const float* Wproj = (const float*)d_in[3];
    const float* bproj = (const float*)d_in[4];
    float* out = (float*)d_out;

    // Workspace (~56 MB)
    float* Pnum = (float*)d_ws;                              // 7*24*784*64 f
    float* Pden = Pnum + (size_t)KSPLIT * 24 * NQ * HD;      // 7*24*784 f
    unsigned short* Qpb = (unsigned short*)(Pden + (size_t)KSPLIT * 24 * NQ); // 1,204,224 us
    unsigned short* Kb  = Qpb + (size_t)24 * NQ * HD;        // 4,816,896 us
    unsigned short* Vt  = Kb + (size_t)BB * NK * DIMO;       // 4,816,896 us
    unsigned short* Wb  = Vt + (size_t)24 * HD * NK;         // 55,296 us
    unsigned short* Wpb = Wb + (size_t)576 * 96;             // 36,864 us

    // 1) weight prep
    wprep<<<24, 256, 0, stream>>>(Wqkv, Wproj, Wb, Wpb);

    // 2) fused qkv GEMM + Q-maxpool (KV merged: 392 + Q: 224 blocks)
    qkv_fused<<<616, 256, 0, stream>>>(x, Wb, bqkv, Qpb, Kb, Vt);

    // 3) MFMA attention partials (R8 geometry)
    attn_mfma<<<dim3(7, 24, KSPLIT), 256, 0, stream>>>(Qpb, Kb, Vt, Pnum, Pden);

    // 4) fused combine + proj
    proj_comb<<<392, 256, 0, stream>>>(Pnum, Pden, Wpb, bproj, out);
}

// Round 11
// 125.594 us; speedup vs baseline: 1.1218x; 1.1019x over previous
//
#include <hip/hip_runtime.h>

// Problem constants
#define BB    8
#define DIMO  192
#define NH    3
#define HD    64
#define NK    3136   // keys per (b,h)
#define NQ    784    // queries per (b,h)
#define M1    25088  // B*H*W
#define M2    6272   // B*NQ
#define KSPLIT 7
#define KSLICE 448   // 7 stages of 64 keys (exact, no tail)
#define PSTR  56     // P-tile row stride (ushorts): 112 B = 7*16, b128-aligned

// Q pre-scale: 1/sqrt(64) * log2(e)  -> exp(S) computed as exp2(S')
#define QSCALE 0.18033688011112042f

#if __has_builtin(__builtin_amdgcn_mfma_f32_16x16x16bf16_1k)
#define HAVE_MFMA16 1
#else
#define HAVE_MFMA16 0
#endif

#if __has_builtin(__builtin_amdgcn_exp2f)
#define FEXP2(x) __builtin_amdgcn_exp2f(x)
#else
#define FEXP2(x) exp2f(x)
#endif

typedef __bf16 bf16x8 __attribute__((ext_vector_type(8)));
typedef float f32x4  __attribute__((ext_vector_type(4)));
typedef short s16x4  __attribute__((ext_vector_type(4)));

__device__ inline unsigned short f2bf(float f) {
    unsigned int u = __builtin_bit_cast(unsigned int, f);
    u += 0x7FFFu + ((u >> 16) & 1u);
    return (unsigned short)(u >> 16);
}

__device__ inline float bf2f(unsigned short u) {
    unsigned int x = (unsigned int)u << 16;
    return __builtin_bit_cast(float, x);
}

// pack bf16(a) (low) | bf16(b) (high), round-half-up: 2 adds + 1 v_perm
__device__ inline unsigned int pk_bf16(float a, float b) {
    unsigned int ua = __builtin_bit_cast(unsigned int, a) + 0x8000u;
    unsigned int ub = __builtin_bit_cast(unsigned int, b) + 0x8000u;
    return __builtin_amdgcn_perm(ub, ua, 0x07060302u);
}

// ---------------------------------------------------------------------------
// Weight prep: blocks 0..17: W_qkv -> Wb bf16 [576][96]; 18..23: W_proj ->
// Wpb bf16 [192n][192k].
// ---------------------------------------------------------------------------
__global__ void wprep(const float* __restrict__ Wqkv, const float* __restrict__ Wproj,
                      unsigned short* __restrict__ Wb, unsigned short* __restrict__ Wpb) {
    __shared__ float Ls[192][33];
    const int t = threadIdx.x;
    if (blockIdx.x < 18) {
        const int n0 = blockIdx.x * 32;
        int rr = t >> 5, c = t & 31;
#pragma unroll
        for (int rb = 0; rb < 12; ++rb) {
            int row = rb * 8 + rr;
            Ls[row][c] = Wqkv[(size_t)row * 576 + n0 + c];
        }
        __syncthreads();
        int n = t >> 3, kc = (t & 7) * 12;
#pragma unroll
        for (int j = 0; j < 12; j += 4) {
            ushort4 u = { f2bf(Ls[kc + j][n]), f2bf(Ls[kc + j + 1][n]),
                          f2bf(Ls[kc + j + 2][n]), f2bf(Ls[kc + j + 3][n]) };
            *(ushort4*)(Wb + (size_t)(n0 + n) * 96 + kc + j) = u;
        }
    } else {
        const int n0 = (blockIdx.x - 18) * 32;
        int rr = t >> 5, c = t & 31;
#pragma unroll
        for (int rb = 0; rb < 24; ++rb) {
            int row = rb * 8 + rr;
            Ls[row][c] = Wproj[(size_t)row * 192 + n0 + c];
        }
        __syncthreads();
        int n = t >> 3, kc = (t & 7) * 24;
#pragma unroll
        for (int j = 0; j < 24; j += 4) {
            ushort4 u = { f2bf(Ls[kc + j][n]), f2bf(Ls[kc + j + 1][n]),
                          f2bf(Ls[kc + j + 2][n]), f2bf(Ls[kc + j + 3][n]) };
            *(ushort4*)(Wpb + (size_t)(n0 + n) * 192 + kc + j) = u;
        }
    }
}

// ---------------------------------------------------------------------------
// Fused qkv GEMM + Q-maxpool. 1008 blocks (R8 geometry — unmerged KV for max
// parallelism; K block i and V block i+392 share an XCD since 392%8==0):
//   bid <  392: K section -> Kb;  bid < 784: V section -> Vt (transposed);
//   bid >= 784: Q section (112-row tile, pool-permuted rows), scale QSCALE.
// ---------------------------------------------------------------------------
__launch_bounds__(256)
__global__ void qkv_fused(const float* __restrict__ x,
                          const unsigned short* __restrict__ Wb,
                          const float* __restrict__ bias,
                          unsigned short* __restrict__ Qpb,
                          unsigned short* __restrict__ Kb,
                          unsigned short* __restrict__ Vt) {
    __shared__ __attribute__((aligned(16))) unsigned short xs[112 * 104]; // 208B rows
    const int tid = threadIdx.x;
    const int wave = tid >> 6, lane = tid & 63;
    const int quad = lane >> 4, l16 = lane & 15;
    const int bid = blockIdx.x;

    if (bid < 784) {
        const int sec = (bid < 392) ? 1 : 2;
        const int m0 = ((bid < 392) ? bid : bid - 392) * 64;
#pragma unroll
        for (int i = 0; i < 6; ++i) {
            int f = tid + i * 256;
            int r = f / 24, c4 = f % 24;
            float4 v = ((const float4*)x)[(size_t)(m0 + r) * 24 + c4];
            ushort4 u = { f2bf(v.x), f2bf(v.y), f2bf(v.z), f2bf(v.w) };
            *(ushort4*)&xs[r * 104 + c4 * 4] = u;
        }
        __syncthreads();

        f32x4 acc[12];
#pragma unroll
        for (int i = 0; i < 12; ++i) acc[i] = (f32x4){0.f, 0.f, 0.f, 0.f};

        const unsigned short* wb = Wb + (size_t)(sec * 192 + l16) * 96 + quad * 8;
#pragma unroll
        for (int ch = 0; ch < 3; ++ch) {
            bf16x8 af = *(const bf16x8*)&xs[(wave * 16 + l16) * 104 + ch * 32 + quad * 8];
#pragma unroll
            for (int nf = 0; nf < 12; ++nf) {
                bf16x8 bfr = *(const bf16x8*)(wb + (size_t)nf * 16 * 96 + ch * 32);
                acc[nf] = __builtin_amdgcn_mfma_f32_16x16x32_bf16(af, bfr, acc[nf], 0, 0, 0);
            }
        }

        const int mbase = m0 + wave * 16 + quad * 4;
        if (sec == 1) {
#pragma unroll
            for (int nf = 0; nf < 12; ++nf) {
                int n = nf * 16 + l16;
                float bs = bias[192 + n];
#pragma unroll
                for (int i = 0; i < 4; ++i)
                    Kb[(size_t)(mbase + i) * 192 + n] = f2bf(acc[nf][i] + bs);
            }
        } else {
            int b = m0 / NK;
            int key = mbase - b * NK;
#pragma unroll
            for (int nf = 0; nf < 12; ++nf) {
                int n = nf * 16 + l16;
                float bs = bias[384 + n];
                int hh = n >> 6, dd = n & 63;
                ushort4 u = { f2bf(acc[nf][0] + bs), f2bf(acc[nf][1] + bs),
                              f2bf(acc[nf][2] + bs), f2bf(acc[nf][3] + bs) };
                *(ushort4*)(Vt + ((size_t)((b * 3 + hh) * 64 + dd)) * NK + key) = u;
            }
        }
    } else {
        const int t = bid - 784;
        const int b = t / 28, hq = t % 28;
        const int m0 = b * NK + hq * 112;
#pragma unroll
        for (int i = 0; i < 11; ++i) {
            int f = tid + i * 256;
            if (f < 2688) {
                int r = f / 24, c4 = f % 24;
                float4 v = ((const float4*)x)[(size_t)(m0 + r) * 24 + c4];
                int rp = 2 * (r % 56) + (r / 56);   // row' = 2x + dy
                ushort4 u = { f2bf(v.x), f2bf(v.y), f2bf(v.z), f2bf(v.w) };
                *(ushort4*)&xs[rp * 104 + c4 * 4] = u;
            }
        }
        __syncthreads();

        f32x4 acc[7][3];
#pragma unroll
        for (int i = 0; i < 7; ++i)
#pragma unroll
            for (int j = 0; j < 3; ++j) acc[i][j] = (f32x4){0.f, 0.f, 0.f, 0.f};

        const unsigned short* wb = Wb + (size_t)(wave * 48 + l16) * 96 + quad * 8;
#pragma unroll
        for (int ch = 0; ch < 3; ++ch) {
            bf16x8 bfr[3];
#pragma unroll
            for (int jf = 0; jf < 3; ++jf)
                bfr[jf] = *(const bf16x8*)(wb + (size_t)jf * 16 * 96 + ch * 32);
#pragma unroll
            for (int mf = 0; mf < 7; ++mf) {
                bf16x8 a = *(const bf16x8*)&xs[(mf * 16 + l16) * 104 + ch * 32 + quad * 8];
#pragma unroll
                for (int jf = 0; jf < 3; ++jf)
                    acc[mf][jf] = __builtin_amdgcn_mfma_f32_16x16x32_bf16(a, bfr[jf], acc[mf][jf], 0, 0, 0);
            }
        }

#pragma unroll
        for (int mf = 0; mf < 7; ++mf) {
            int q = hq * 28 + mf * 4 + quad;
#pragma unroll
            for (int jf = 0; jf < 3; ++jf) {
                int n = wave * 48 + jf * 16 + l16;
                float m = fmaxf(fmaxf(acc[mf][jf][0], acc[mf][jf][1]),
                                fmaxf(acc[mf][jf][2], acc[mf][jf][3]));
                m = (m + bias[n]) * QSCALE;
                int hh = n >> 6, dd = n & 63;
                Qpb[((size_t)(b * 3 + hh) * NQ + q) * 64 + dd] = f2bf(m);
            }
        }
    }
}

// ---------------------------------------------------------------------------
// MFMA attention. 1D grid 1176 blocks, XCD-aware: all 49 blocks (7 qt x 7 ks)
// of one bh land on one XCD (bh = (bid&7)*3 + (bid>>3)/49) -> K/V re-reads
// hit that XCD's L2 (~800 KB/bh working set). 4 waves x 32q. exp2 P,
// v_perm bf16 pack, den via ones-MFMA. Pnum partials stored bf16.
// ---------------------------------------------------------------------------
__launch_bounds__(256)
__global__ void attn_mfma(const unsigned short* __restrict__ Qpb,
                          const unsigned short* __restrict__ Kb,
                          const unsigned short* __restrict__ Vt,
                          unsigned short* __restrict__ Pnum,
                          float* __restrict__ Pden) {
    __shared__ __attribute__((aligned(16))) unsigned short Ks[64 * 88];  // [key][d]
    __shared__ __attribute__((aligned(16))) unsigned short Vs[64 * 88];  // [d][key]
#if !HAVE_MFMA16
    __shared__ __attribute__((aligned(16))) unsigned short Ps[4 * 32 * PSTR];
#endif

    const int tid = threadIdx.x;
    const int wave = tid >> 6, lane = tid & 63;
    const int quad = lane >> 4, l16 = lane & 15;

    const int bid = blockIdx.x;
    const int xcd = bid & 7, slot = bid >> 3;      // slot 0..146
    const int bh = xcd * 3 + slot / 49;
    const int inner = slot % 49;
    const int qt = (inner / 7) * 128 + wave * 32;
    const int ks = inner % 7;

    const int b = bh / NH, h = bh % NH;
    const int k00 = ks * KSLICE;

    const int srow0 = tid >> 3, sch = (tid & 7) * 8;
    const unsigned short* kg  = Kb + ((size_t)(b * NK + k00) + srow0) * DIMO + h * 64 + sch;
    const unsigned short* kg1 = kg + (size_t)32 * DIMO;
    const unsigned short* vg  = Vt + ((size_t)bh * 64 + srow0) * NK + k00 + sch;
    const unsigned short* vg1 = vg + (size_t)32 * NK;

    uint4 kp0 = *(const uint4*)kg;
    uint4 kp1 = *(const uint4*)kg1;
    uint4 vp0 = *(const uint4*)vg;
    uint4 vp1 = *(const uint4*)vg1;

    // Q B-frags: lane holds q=l16 (+16*qsub), d=quad*8+j (+32*chunk)
    int qa = min(qt + l16, NQ - 1);
    int qb = min(qt + 16 + l16, NQ - 1);
    const unsigned short* qpa = Qpb + ((size_t)bh * NQ + qa) * HD + quad * 8;
    const unsigned short* qpc = Qpb + ((size_t)bh * NQ + qb) * HD + quad * 8;
    bf16x8 qf[2][2];
    qf[0][0] = *(const bf16x8*)qpa;  qf[0][1] = *(const bf16x8*)(qpa + 32);
    qf[1][0] = *(const bf16x8*)qpc;  qf[1][1] = *(const bf16x8*)(qpc + 32);

    f32x4 on[4][2];
#pragma unroll
    for (int i = 0; i < 4; ++i)
#pragma unroll
        for (int j = 0; j < 2; ++j) on[i][j] = (f32x4){0.f, 0.f, 0.f, 0.f};
    f32x4 dn[2];
    dn[0] = (f32x4){0.f, 0.f, 0.f, 0.f};
    dn[1] = (f32x4){0.f, 0.f, 0.f, 0.f};

#if HAVE_MFMA16
    const short one16 = (short)0x3F80;           // bf16 1.0
    s16x4 ones4 = { one16, one16, one16, one16 };
#else
    const __bf16 one = (__bf16)1.0f;
    bf16x8 ones8 = { one, one, one, one, one, one, one, one };
    unsigned short* myP = Ps + wave * 32 * PSTR;
#endif

    for (int s = 0; s < 7; ++s) {
        __syncthreads();
        *(uint4*)&Ks[srow0 * 88 + sch]        = kp0;
        *(uint4*)&Ks[(srow0 + 32) * 88 + sch] = kp1;
        *(uint4*)&Vs[srow0 * 88 + sch]        = vp0;
        *(uint4*)&Vs[(srow0 + 32) * 88 + sch] = vp1;
        __syncthreads();
        if (s < 6) {
            kp0 = *(const uint4*)(kg  + (size_t)(s + 1) * 64 * DIMO);
            kp1 = *(const uint4*)(kg1 + (size_t)(s + 1) * 64 * DIMO);
            vp0 = *(const uint4*)(vg  + (s + 1) * 64);
            vp1 = *(const uint4*)(vg1 + (s + 1) * 64);
        }

#if HAVE_MFMA16
#pragma unroll
        for (int g = 0; g < 4; ++g) {
            const int krow = (g * 16 + l16) * 88;
            bf16x8 kf0 = *(const bf16x8*)&Ks[krow + quad * 8];
            bf16x8 kf1 = *(const bf16x8*)&Ks[krow + 32 + quad * 8];
            s16x4 vf[4];
#pragma unroll
            for (int dsub = 0; dsub < 4; ++dsub)
                vf[dsub] = *(const s16x4*)&Vs[(dsub * 16 + l16) * 88 + g * 16 + quad * 4];
#pragma unroll
            for (int qsub = 0; qsub < 2; ++qsub) {
                f32x4 sa = (f32x4){0.f, 0.f, 0.f, 0.f};
                sa = __builtin_amdgcn_mfma_f32_16x16x32_bf16(kf0, qf[qsub][0], sa, 0, 0, 0);
                sa = __builtin_amdgcn_mfma_f32_16x16x32_bf16(kf1, qf[qsub][1], sa, 0, 0, 0);
                float p0 = FEXP2(sa[0]), p1 = FEXP2(sa[1]);
                float p2 = FEXP2(sa[2]), p3 = FEXP2(sa[3]);
                uint2 pk = { pk_bf16(p0, p1), pk_bf16(p2, p3) };
                s16x4 pb = __builtin_bit_cast(s16x4, pk);
                dn[qsub] = __builtin_amdgcn_mfma_f32_16x16x16bf16_1k(ones4, pb, dn[qsub], 0, 0, 0);
#pragma unroll
                for (int dsub = 0; dsub < 4; ++dsub)
                    on[dsub][qsub] = __builtin_amdgcn_mfma_f32_16x16x16bf16_1k(
                        vf[dsub], pb, on[dsub][qsub], 0, 0, 0);
            }
        }
#else
#pragma unroll
        for (int half = 0; half < 2; ++half) {
#pragma unroll
            for (int ksub = 0; ksub < 2; ++ksub) {
                const int krow = (half * 32 + ksub * 16 + l16) * 88;
                bf16x8 kf0 = *(const bf16x8*)&Ks[krow + quad * 8];
                bf16x8 kf1 = *(const bf16x8*)&Ks[krow + 32 + quad * 8];
#pragma unroll
                for (int qsub = 0; qsub < 2; ++qsub) {
                    f32x4 sa = (f32x4){0.f, 0.f, 0.f, 0.f};
                    sa = __builtin_amdgcn_mfma_f32_16x16x32_bf16(kf0, qf[qsub][0], sa, 0, 0, 0);
                    sa = __builtin_amdgcn_mfma_f32_16x16x32_bf16(kf1, qf[qsub][1], sa, 0, 0, 0);
                    float p0 = FEXP2(sa[0]), p1 = FEXP2(sa[1]);
                    float p2 = FEXP2(sa[2]), p3 = FEXP2(sa[3]);
                    uint2 pk = { pk_bf16(p0, p1), pk_bf16(p2, p3) };
                    *(uint2*)&myP[(qsub * 16 + l16) * PSTR + ksub * 16 + quad * 4] = pk;
                }
            }
            bf16x8 pf0 = *(const bf16x8*)&myP[l16 * PSTR + quad * 8];
            bf16x8 pf1 = *(const bf16x8*)&myP[(16 + l16) * PSTR + quad * 8];
            dn[0] = __builtin_amdgcn_mfma_f32_16x16x32_bf16(ones8, pf0, dn[0], 0, 0, 0);
            dn[1] = __builtin_amdgcn_mfma_f32_16x16x32_bf16(ones8, pf1, dn[1], 0, 0, 0);
#pragma unroll
            for (int dsub = 0; dsub < 4; ++dsub) {
                bf16x8 vf = *(const bf16x8*)&Vs[(dsub * 16 + l16) * 88 + half * 32 + quad * 8];
                on[dsub][0] = __builtin_amdgcn_mfma_f32_16x16x32_bf16(vf, pf0, on[dsub][0], 0, 0, 0);
                on[dsub][1] = __builtin_amdgcn_mfma_f32_16x16x32_bf16(vf, pf1, on[dsub][1], 0, 0, 0);
            }
        }
#endif
    }

#pragma unroll
    for (int qsub = 0; qsub < 2; ++qsub) {
        int q = qt + qsub * 16 + l16;
        if (q < NQ) {
            size_t base = (size_t)ks * (24 * NQ * HD) + ((size_t)bh * NQ + q) * HD + quad * 4;
#pragma unroll
            for (int dsub = 0; dsub < 4; ++dsub) {
                uint2 pk = { pk_bf16(on[dsub][qsub][0], on[dsub][qsub][1]),
                             pk_bf16(on[dsub][qsub][2], on[dsub][qsub][3]) };
                *(uint2*)(Pnum + base + dsub * 16) = pk;
            }
            if (quad == 0) Pden[ks * (24 * NQ) + bh * NQ + q] = dn[qsub][0];
        }
    }
}

// ---------------------------------------------------------------------------
// Fused combine + proj. Grid 392 = 8 batches x 49 tiles, batch = bid&7 so a
// batch's blocks land on the XCD whose L2 holds its attn partials.
// ---------------------------------------------------------------------------
__launch_bounds__(256)
__global__ void proj_comb(const unsigned short* __restrict__ Pnum,
                          const float* __restrict__ Pden,
                          const unsigned short* __restrict__ Wpb,
                          const float* __restrict__ bproj,
                          float* __restrict__ out) {
    __shared__ __attribute__((aligned(16))) unsigned short as_[16 * 200]; // 400B rows
    __shared__ float rden[16][4];
    const int tid = threadIdx.x;
    const int wave = tid >> 6, lane = tid & 63;
    const int quad = lane >> 4, l16 = lane & 15;
    const int bb_ = blockIdx.x & 7;
    const int m0 = bb_ * NQ + (blockIdx.x >> 3) * 16;

    if (tid < 48) {
        int r = tid / 3, h = tid % 3;
        int qq = m0 + r - bb_ * NQ;
        float den = 0.f;
#pragma unroll
        for (int s = 0; s < KSPLIT; ++s)
            den += Pden[s * (24 * NQ) + (bb_ * 3 + h) * NQ + qq];
        rden[r][h] = 1.0f / den;
    }
    __syncthreads();

    {
        int r = tid >> 4, cl = tid & 15;
        int qq = m0 + r - bb_ * NQ;
#pragma unroll
        for (int i = 0; i < 3; ++i) {
            int c = cl + i * 16;           // 0..47 (4-elem chunks of the 192 cols)
            int h = c >> 4, d = (c & 15) * 4;
            const unsigned short* p = Pnum + ((size_t)(bb_ * 3 + h) * NQ + qq) * 64 + d;
            f32x4 num = (f32x4){0.f, 0.f, 0.f, 0.f};
#pragma unroll
            for (int s = 0; s < KSPLIT; ++s) {
                ushort4 u4 = *(const ushort4*)(p + (size_t)s * (24 * NQ * HD));
                num[0] += bf2f(u4.x); num[1] += bf2f(u4.y);
                num[2] += bf2f(u4.z); num[3] += bf2f(u4.w);
            }
            float rc = rden[r][h];
            ushort4 u = { f2bf(num[0] * rc), f2bf(num[1] * rc),
                          f2bf(num[2] * rc), f2bf(num[3] * rc) };
            *(ushort4*)&as_[r * 200 + c * 4] = u;
        }
    }
    __syncthreads();

    f32x4 acc[3];
#pragma unroll
    for (int j = 0; j < 3; ++j) acc[j] = (f32x4){0.f, 0.f, 0.f, 0.f};

    const unsigned short* wp = Wpb + (size_t)(wave * 48 + l16) * 192 + quad * 8;
#pragma unroll
    for (int ch = 0; ch < 6; ++ch) {
        bf16x8 a = *(const bf16x8*)&as_[l16 * 200 + ch * 32 + quad * 8];
#pragma unroll
        for (int jf = 0; jf < 3; ++jf) {
            bf16x8 bfr = *(const bf16x8*)(wp + (size_t)jf * 16 * 192 + ch * 32);
            acc[jf] = __builtin_amdgcn_mfma_f32_16x16x32_bf16(a, bfr, acc[jf], 0, 0, 0);
        }
    }

    const int m = m0 + quad * 4;
#pragma unroll
    for (int jf = 0; jf < 3; ++jf) {
        int n = wave * 48 + jf * 16 + l16;
        float bs = bproj[n];
#pragma unroll
        for (int i = 0; i < 4; ++i)
            out[(size_t)(m + i) * 192 + n] = acc[jf][i] + bs;
    }
}

// ---------------------------------------------------------------------------
extern "C" void kernel_launch(void* const* d_in, const int* in_sizes, int n_in,
                              void* d_out, int out_size, void* d_ws, size_t ws_size,
                              hipStream_t stream) {
    const float* x     = (const float*)d_in[0];
    const float* Wqkv  = (const float*)d_in[1];
    const float* bqkv  = (const float*)d_in[2];
    const float* Wproj = (const float*)d_in[3];
    const float* bproj = (const float*)d_in[4];
    float* out = (float*)d_out;

    // Workspace (~40 MB)
    unsigned short* Pnum = (unsigned short*)d_ws;            // 7*24*784*64 us (bf16)
    float* Pden = (float*)(Pnum + (size_t)KSPLIT * 24 * NQ * HD); // 7*24*784 f
    unsigned short* Qpb = (unsigned short*)(Pden + (size_t)KSPLIT * 24 * NQ);
    unsigned short* Kb  = Qpb + (size_t)24 * NQ * HD;        // 4,816,896 us
    unsigned short* Vt  = Kb + (size_t)BB * NK * DIMO;       // 4,816,896 us
    unsigned short* Wb  = Vt + (size_t)24 * HD * NK;         // 55,296 us
    unsigned short* Wpb = Wb + (size_t)576 * 96;             // 36,864 us

    // 1) weight prep
    wprep<<<24, 256, 0, stream>>>(Wqkv, Wproj, Wb, Wpb);

    // 2) fused qkv GEMM + Q-maxpool (unmerged: K 392 + V 392 + Q 224 blocks)
    qkv_fused<<<1008, 256, 0, stream>>>(x, Wb, bqkv, Qpb, Kb, Vt);

    // 3) MFMA attention partials (XCD-aware 1D grid)
    attn_mfma<<<1176, 256, 0, stream>>>(Qpb, Kb, Vt, Pnum, Pden);

    // 4) fused combine + proj (batch-per-XCD swizzle)
    proj_comb<<<392, 256, 0, stream>>>(Pnum, Pden, Wpb, bproj, out);
}

// Round 12
// 124.688 us; speedup vs baseline: 1.1300x; 1.0073x over previous
//
#include <hip/hip_runtime.h>

// Problem constants
#define BB    8
#define DIMO  192
#define NH    3
#define HD    64
#define NK    3136   // keys per (b,h)
#define NQ    784    // queries per (b,h)
#define M1    25088  // B*H*W
#define M2    6272   // B*NQ
#define KSPLIT 7
#define KSLICE 448   // 7 stages of 64 keys (exact, no tail)
#define PSTR  56     // P-tile row stride (ushorts): 112 B = 7*16, b128-aligned

// Q pre-scale: 1/sqrt(64) * log2(e)  -> exp(S) computed as exp2(S')
#define QSCALE 0.18033688011112042f

#if __has_builtin(__builtin_amdgcn_mfma_f32_16x16x16bf16_1k)
#define HAVE_MFMA16 1
#else
#define HAVE_MFMA16 0
#endif

#if __has_builtin(__builtin_amdgcn_exp2f)
#define FEXP2(x) __builtin_amdgcn_exp2f(x)
#else
#define FEXP2(x) exp2f(x)
#endif

typedef __bf16 bf16x8 __attribute__((ext_vector_type(8)));
typedef float f32x4  __attribute__((ext_vector_type(4)));
typedef short s16x4  __attribute__((ext_vector_type(4)));

__device__ inline unsigned short f2bf(float f) {
    unsigned int u = __builtin_bit_cast(unsigned int, f);
    u += 0x7FFFu + ((u >> 16) & 1u);
    return (unsigned short)(u >> 16);
}

__device__ inline float bf2f(unsigned short u) {
    unsigned int x = (unsigned int)u << 16;
    return __builtin_bit_cast(float, x);
}

// pack bf16(a) (low) | bf16(b) (high), round-half-up: 2 adds + 1 v_perm
__device__ inline unsigned int pk_bf16(float a, float b) {
    unsigned int ua = __builtin_bit_cast(unsigned int, a) + 0x8000u;
    unsigned int ub = __builtin_bit_cast(unsigned int, b) + 0x8000u;
    return __builtin_amdgcn_perm(ub, ua, 0x07060302u);
}

// ---------------------------------------------------------------------------
// Weight prep: blocks 0..17: W_qkv -> Wb bf16 [576][96]; 18..23: W_proj ->
// Wpb bf16 [192n][192k].
// ---------------------------------------------------------------------------
__global__ void wprep(const float* __restrict__ Wqkv, const float* __restrict__ Wproj,
                      unsigned short* __restrict__ Wb, unsigned short* __restrict__ Wpb) {
    __shared__ float Ls[192][33];
    const int t = threadIdx.x;
    if (blockIdx.x < 18) {
        const int n0 = blockIdx.x * 32;
        int rr = t >> 5, c = t & 31;
#pragma unroll
        for (int rb = 0; rb < 12; ++rb) {
            int row = rb * 8 + rr;
            Ls[row][c] = Wqkv[(size_t)row * 576 + n0 + c];
        }
        __syncthreads();
        int n = t >> 3, kc = (t & 7) * 12;
#pragma unroll
        for (int j = 0; j < 12; j += 4) {
            ushort4 u = { f2bf(Ls[kc + j][n]), f2bf(Ls[kc + j + 1][n]),
                          f2bf(Ls[kc + j + 2][n]), f2bf(Ls[kc + j + 3][n]) };
            *(ushort4*)(Wb + (size_t)(n0 + n) * 96 + kc + j) = u;
        }
    } else {
        const int n0 = (blockIdx.x - 18) * 32;
        int rr = t >> 5, c = t & 31;
#pragma unroll
        for (int rb = 0; rb < 24; ++rb) {
            int row = rb * 8 + rr;
            Ls[row][c] = Wproj[(size_t)row * 192 + n0 + c];
        }
        __syncthreads();
        int n = t >> 3, kc = (t & 7) * 24;
#pragma unroll
        for (int j = 0; j < 24; j += 4) {
            ushort4 u = { f2bf(Ls[kc + j][n]), f2bf(Ls[kc + j + 1][n]),
                          f2bf(Ls[kc + j + 2][n]), f2bf(Ls[kc + j + 3][n]) };
            *(ushort4*)(Wpb + (size_t)(n0 + n) * 192 + kc + j) = u;
        }
    }
}

// ---------------------------------------------------------------------------
// Fused qkv GEMM + Q-maxpool. 1008 blocks, batch-aligned XCD swizzle:
// every K/V/Q tile of batch b is issued from a block with bid%8 == b, so it
// is written through XCD b's L2 — the same XCD that attn_mfma later reads
// batch b from (attn maps bh 3b..3b+2 -> XCD b). 392=49*8, 224=28*8 exact.
//   bid <  392: K tile (bid&7)*49+(bid>>3)      -> Kb
//   bid <  784: V tile ((bid-392)&7)*49+...     -> Vt (transposed)
//   bid >= 784: Q 112-row tile, batch (bid-784)&7, row-pair (bid-784)>>3
// ---------------------------------------------------------------------------
__launch_bounds__(256)
__global__ void qkv_fused(const float* __restrict__ x,
                          const unsigned short* __restrict__ Wb,
                          const float* __restrict__ bias,
                          unsigned short* __restrict__ Qpb,
                          unsigned short* __restrict__ Kb,
                          unsigned short* __restrict__ Vt) {
    __shared__ __attribute__((aligned(16))) unsigned short xs[112 * 104]; // 208B rows
    const int tid = threadIdx.x;
    const int wave = tid >> 6, lane = tid & 63;
    const int quad = lane >> 4, l16 = lane & 15;
    const int bid = blockIdx.x;

    if (bid < 784) {
        const int sec = (bid < 392) ? 1 : 2;
        const int i = (bid < 392) ? bid : bid - 392;
        const int tile = (i & 7) * 49 + (i >> 3);   // batch = i&7 -> XCD i&7
        const int m0 = tile * 64;
#pragma unroll
        for (int p = 0; p < 6; ++p) {
            int f = tid + p * 256;
            int r = f / 24, c4 = f % 24;
            float4 v = ((const float4*)x)[(size_t)(m0 + r) * 24 + c4];
            ushort4 u = { f2bf(v.x), f2bf(v.y), f2bf(v.z), f2bf(v.w) };
            *(ushort4*)&xs[r * 104 + c4 * 4] = u;
        }
        __syncthreads();

        f32x4 acc[12];
#pragma unroll
        for (int p = 0; p < 12; ++p) acc[p] = (f32x4){0.f, 0.f, 0.f, 0.f};

        const unsigned short* wb = Wb + (size_t)(sec * 192 + l16) * 96 + quad * 8;
#pragma unroll
        for (int ch = 0; ch < 3; ++ch) {
            bf16x8 af = *(const bf16x8*)&xs[(wave * 16 + l16) * 104 + ch * 32 + quad * 8];
#pragma unroll
            for (int nf = 0; nf < 12; ++nf) {
                bf16x8 bfr = *(const bf16x8*)(wb + (size_t)nf * 16 * 96 + ch * 32);
                acc[nf] = __builtin_amdgcn_mfma_f32_16x16x32_bf16(af, bfr, acc[nf], 0, 0, 0);
            }
        }

        const int mbase = m0 + wave * 16 + quad * 4;
        if (sec == 1) {
#pragma unroll
            for (int nf = 0; nf < 12; ++nf) {
                int n = nf * 16 + l16;
                float bs = bias[192 + n];
#pragma unroll
                for (int p = 0; p < 4; ++p)
                    Kb[(size_t)(mbase + p) * 192 + n] = f2bf(acc[nf][p] + bs);
            }
        } else {
            int b = m0 / NK;
            int key = mbase - b * NK;
#pragma unroll
            for (int nf = 0; nf < 12; ++nf) {
                int n = nf * 16 + l16;
                float bs = bias[384 + n];
                int hh = n >> 6, dd = n & 63;
                ushort4 u = { f2bf(acc[nf][0] + bs), f2bf(acc[nf][1] + bs),
                              f2bf(acc[nf][2] + bs), f2bf(acc[nf][3] + bs) };
                *(ushort4*)(Vt + ((size_t)((b * 3 + hh) * 64 + dd)) * NK + key) = u;
            }
        }
    } else {
        const int i = bid - 784;
        const int b = i & 7, hq = i >> 3;           // batch -> XCD b
        const int m0 = b * NK + hq * 112;
#pragma unroll
        for (int p = 0; p < 11; ++p) {
            int f = tid + p * 256;
            if (f < 2688) {
                int r = f / 24, c4 = f % 24;
                float4 v = ((const float4*)x)[(size_t)(m0 + r) * 24 + c4];
                int rp = 2 * (r % 56) + (r / 56);   // row' = 2x + dy
                ushort4 u = { f2bf(v.x), f2bf(v.y), f2bf(v.z), f2bf(v.w) };
                *(ushort4*)&xs[rp * 104 + c4 * 4] = u;
            }
        }
        __syncthreads();

        f32x4 acc[7][3];
#pragma unroll
        for (int p = 0; p < 7; ++p)
#pragma unroll
            for (int j = 0; j < 3; ++j) acc[p][j] = (f32x4){0.f, 0.f, 0.f, 0.f};

        const unsigned short* wb = Wb + (size_t)(wave * 48 + l16) * 96 + quad * 8;
#pragma unroll
        for (int ch = 0; ch < 3; ++ch) {
            bf16x8 bfr[3];
#pragma unroll
            for (int jf = 0; jf < 3; ++jf)
                bfr[jf] = *(const bf16x8*)(wb + (size_t)jf * 16 * 96 + ch * 32);
#pragma unroll
            for (int mf = 0; mf < 7; ++mf) {
                bf16x8 a = *(const bf16x8*)&xs[(mf * 16 + l16) * 104 + ch * 32 + quad * 8];
#pragma unroll
                for (int jf = 0; jf < 3; ++jf)
                    acc[mf][jf] = __builtin_amdgcn_mfma_f32_16x16x32_bf16(a, bfr[jf], acc[mf][jf], 0, 0, 0);
            }
        }

#pragma unroll
        for (int mf = 0; mf < 7; ++mf) {
            int q = hq * 28 + mf * 4 + quad;
#pragma unroll
            for (int jf = 0; jf < 3; ++jf) {
                int n = wave * 48 + jf * 16 + l16;
                float m = fmaxf(fmaxf(acc[mf][jf][0], acc[mf][jf][1]),
                                fmaxf(acc[mf][jf][2], acc[mf][jf][3]));
                m = (m + bias[n]) * QSCALE;
                int hh = n >> 6, dd = n & 63;
                Qpb[((size_t)(b * 3 + hh) * NQ + q) * 64 + dd] = f2bf(m);
            }
        }
    }
}

// ---------------------------------------------------------------------------
// MFMA attention. 1D grid 1176 blocks, XCD-aware: all 147 blocks of batch b
// land on XCD b (bh = (bid&7)*3 + (bid>>3)/49), whose L2 holds that batch's
// K/V (written there by qkv_fused's matching swizzle). 4 waves x 32q.
// exp2 P, v_perm bf16 pack, den via ones-MFMA. Pnum partials bf16.
// ---------------------------------------------------------------------------
__launch_bounds__(256)
__global__ void attn_mfma(const unsigned short* __restrict__ Qpb,
                          const unsigned short* __restrict__ Kb,
                          const unsigned short* __restrict__ Vt,
                          unsigned short* __restrict__ Pnum,
                          float* __restrict__ Pden) {
    __shared__ __attribute__((aligned(16))) unsigned short Ks[64 * 88];  // [key][d]
    __shared__ __attribute__((aligned(16))) unsigned short Vs[64 * 88];  // [d][key]
#if !HAVE_MFMA16
    __shared__ __attribute__((aligned(16))) unsigned short Ps[4 * 32 * PSTR];
#endif

    const int tid = threadIdx.x;
    const int wave = tid >> 6, lane = tid & 63;
    const int quad = lane >> 4, l16 = lane & 15;

    const int bid = blockIdx.x;
    const int xcd = bid & 7, slot = bid >> 3;      // slot 0..146
    const int bh = xcd * 3 + slot / 49;
    const int inner = slot % 49;
    const int qt = (inner / 7) * 128 + wave * 32;
    const int ks = inner % 7;

    const int b = bh / NH, h = bh % NH;
    const int k00 = ks * KSLICE;

    const int srow0 = tid >> 3, sch = (tid & 7) * 8;
    const unsigned short* kg  = Kb + ((size_t)(b * NK + k00) + srow0) * DIMO + h * 64 + sch;
    const unsigned short* kg1 = kg + (size_t)32 * DIMO;
    const unsigned short* vg  = Vt + ((size_t)bh * 64 + srow0) * NK + k00 + sch;
    const unsigned short* vg1 = vg + (size_t)32 * NK;

    uint4 kp0 = *(const uint4*)kg;
    uint4 kp1 = *(const uint4*)kg1;
    uint4 vp0 = *(const uint4*)vg;
    uint4 vp1 = *(const uint4*)vg1;

    // Q B-frags: lane holds q=l16 (+16*qsub), d=quad*8+j (+32*chunk)
    int qa = min(qt + l16, NQ - 1);
    int qb = min(qt + 16 + l16, NQ - 1);
    const unsigned short* qpa = Qpb + ((size_t)bh * NQ + qa) * HD + quad * 8;
    const unsigned short* qpc = Qpb + ((size_t)bh * NQ + qb) * HD + quad * 8;
    bf16x8 qf[2][2];
    qf[0][0] = *(const bf16x8*)qpa;  qf[0][1] = *(const bf16x8*)(qpa + 32);
    qf[1][0] = *(const bf16x8*)qpc;  qf[1][1] = *(const bf16x8*)(qpc + 32);

    f32x4 on[4][2];
#pragma unroll
    for (int i = 0; i < 4; ++i)
#pragma unroll
        for (int j = 0; j < 2; ++j) on[i][j] = (f32x4){0.f, 0.f, 0.f, 0.f};
    f32x4 dn[2];
    dn[0] = (f32x4){0.f, 0.f, 0.f, 0.f};
    dn[1] = (f32x4){0.f, 0.f, 0.f, 0.f};

#if HAVE_MFMA16
    const short one16 = (short)0x3F80;           // bf16 1.0
    s16x4 ones4 = { one16, one16, one16, one16 };
#else
    const __bf16 one = (__bf16)1.0f;
    bf16x8 ones8 = { one, one, one, one, one, one, one, one };
    unsigned short* myP = Ps + wave * 32 * PSTR;
#endif

    for (int s = 0; s < 7; ++s) {
        __syncthreads();
        *(uint4*)&Ks[srow0 * 88 + sch]        = kp0;
        *(uint4*)&Ks[(srow0 + 32) * 88 + sch] = kp1;
        *(uint4*)&Vs[srow0 * 88 + sch]        = vp0;
        *(uint4*)&Vs[(srow0 + 32) * 88 + sch] = vp1;
        __syncthreads();
        if (s < 6) {
            kp0 = *(const uint4*)(kg  + (size_t)(s + 1) * 64 * DIMO);
            kp1 = *(const uint4*)(kg1 + (size_t)(s + 1) * 64 * DIMO);
            vp0 = *(const uint4*)(vg  + (s + 1) * 64);
            vp1 = *(const uint4*)(vg1 + (s + 1) * 64);
        }

#if HAVE_MFMA16
#pragma unroll
        for (int g = 0; g < 4; ++g) {
            const int krow = (g * 16 + l16) * 88;
            bf16x8 kf0 = *(const bf16x8*)&Ks[krow + quad * 8];
            bf16x8 kf1 = *(const bf16x8*)&Ks[krow + 32 + quad * 8];
            s16x4 vf[4];
#pragma unroll
            for (int dsub = 0; dsub < 4; ++dsub)
                vf[dsub] = *(const s16x4*)&Vs[(dsub * 16 + l16) * 88 + g * 16 + quad * 4];
#pragma unroll
            for (int qsub = 0; qsub < 2; ++qsub) {
                f32x4 sa = (f32x4){0.f, 0.f, 0.f, 0.f};
                sa = __builtin_amdgcn_mfma_f32_16x16x32_bf16(kf0, qf[qsub][0], sa, 0, 0, 0);
                sa = __builtin_amdgcn_mfma_f32_16x16x32_bf16(kf1, qf[qsub][1], sa, 0, 0, 0);
                float p0 = FEXP2(sa[0]), p1 = FEXP2(sa[1]);
                float p2 = FEXP2(sa[2]), p3 = FEXP2(sa[3]);
                uint2 pk = { pk_bf16(p0, p1), pk_bf16(p2, p3) };
                s16x4 pb = __builtin_bit_cast(s16x4, pk);
                dn[qsub] = __builtin_amdgcn_mfma_f32_16x16x16bf16_1k(ones4, pb, dn[qsub], 0, 0, 0);
#pragma unroll
                for (int dsub = 0; dsub < 4; ++dsub)
                    on[dsub][qsub] = __builtin_amdgcn_mfma_f32_16x16x16bf16_1k(
                        vf[dsub], pb, on[dsub][qsub], 0, 0, 0);
            }
        }
#else
#pragma unroll
        for (int half = 0; half < 2; ++half) {
#pragma unroll
            for (int ksub = 0; ksub < 2; ++ksub) {
                const int krow = (half * 32 + ksub * 16 + l16) * 88;
                bf16x8 kf0 = *(const bf16x8*)&Ks[krow + quad * 8];
                bf16x8 kf1 = *(const bf16x8*)&Ks[krow + 32 + quad * 8];
#pragma unroll
                for (int qsub = 0; qsub < 2; ++qsub) {
                    f32x4 sa = (f32x4){0.f, 0.f, 0.f, 0.f};
                    sa = __builtin_amdgcn_mfma_f32_16x16x32_bf16(kf0, qf[qsub][0], sa, 0, 0, 0);
                    sa = __builtin_amdgcn_mfma_f32_16x16x32_bf16(kf1, qf[qsub][1], sa, 0, 0, 0);
                    float p0 = FEXP2(sa[0]), p1 = FEXP2(sa[1]);
                    float p2 = FEXP2(sa[2]), p3 = FEXP2(sa[3]);
                    uint2 pk = { pk_bf16(p0, p1), pk_bf16(p2, p3) };
                    *(uint2*)&myP[(qsub * 16 + l16) * PSTR + ksub * 16 + quad * 4] = pk;
                }
            }
            bf16x8 pf0 = *(const bf16x8*)&myP[l16 * PSTR + quad * 8];
            bf16x8 pf1 = *(const bf16x8*)&myP[(16 + l16) * PSTR + quad * 8];
            dn[0] = __builtin_amdgcn_mfma_f32_16x16x32_bf16(ones8, pf0, dn[0], 0, 0, 0);
            dn[1] = __builtin_amdgcn_mfma_f32_16x16x32_bf16(ones8, pf1, dn[1], 0, 0, 0);
#pragma unroll
            for (int dsub = 0; dsub < 4; ++dsub) {
                bf16x8 vf = *(const bf16x8*)&Vs[(dsub * 16 + l16) * 88 + half * 32 + quad * 8];
                on[dsub][0] = __builtin_amdgcn_mfma_f32_16x16x32_bf16(vf, pf0, on[dsub][0], 0, 0, 0);
                on[dsub][1] = __builtin_amdgcn_mfma_f32_16x16x32_bf16(vf, pf1, on[dsub][1], 0, 0, 0);
            }
        }
#endif
    }

#pragma unroll
    for (int qsub = 0; qsub < 2; ++qsub) {
        int q = qt + qsub * 16 + l16;
        if (q < NQ) {
            size_t base = (size_t)ks * (24 * NQ * HD) + ((size_t)bh * NQ + q) * HD + quad * 4;
#pragma unroll
            for (int dsub = 0; dsub < 4; ++dsub) {
                uint2 pk = { pk_bf16(on[dsub][qsub][0], on[dsub][qsub][1]),
                             pk_bf16(on[dsub][qsub][2], on[dsub][qsub][3]) };
                *(uint2*)(Pnum + base + dsub * 16) = pk;
            }
            if (quad == 0) Pden[ks * (24 * NQ) + bh * NQ + q] = dn[qsub][0];
        }
    }
}

// ---------------------------------------------------------------------------
// Fused combine + proj. Grid 392 = 8 batches x 49 tiles, batch = bid&7 so a
// batch's blocks land on the XCD whose L2 holds its attn partials.
// ---------------------------------------------------------------------------
__launch_bounds__(256)
__global__ void proj_comb(const unsigned short* __restrict__ Pnum,
                          const float* __restrict__ Pden,
                          const unsigned short* __restrict__ Wpb,
                          const float* __restrict__ bproj,
                          float* __restrict__ out) {
    __shared__ __attribute__((aligned(16))) unsigned short as_[16 * 200]; // 400B rows
    __shared__ float rden[16][4];
    const int tid = threadIdx.x;
    const int wave = tid >> 6, lane = tid & 63;
    const int quad = lane >> 4, l16 = lane & 15;
    const int bb_ = blockIdx.x & 7;
    const int m0 = bb_ * NQ + (blockIdx.x >> 3) * 16;

    if (tid < 48) {
        int r = tid / 3, h = tid % 3;
        int qq = m0 + r - bb_ * NQ;
        float den = 0.f;
#pragma unroll
        for (int s = 0; s < KSPLIT; ++s)
            den += Pden[s * (24 * NQ) + (bb_ * 3 + h) * NQ + qq];
        rden[r][h] = 1.0f / den;
    }
    __syncthreads();

    {
        int r = tid >> 4, cl = tid & 15;
        int qq = m0 + r - bb_ * NQ;
#pragma unroll
        for (int i = 0; i < 3; ++i) {
            int c = cl + i * 16;           // 0..47 (4-elem chunks of the 192 cols)
            int h = c >> 4, d = (c & 15) * 4;
            const unsigned short* p = Pnum + ((size_t)(bb_ * 3 + h) * NQ + qq) * 64 + d;
            f32x4 num = (f32x4){0.f, 0.f, 0.f, 0.f};
#pragma unroll
            for (int s = 0; s < KSPLIT; ++s) {
                ushort4 u4 = *(const ushort4*)(p + (size_t)s * (24 * NQ * HD));
                num[0] += bf2f(u4.x); num[1] += bf2f(u4.y);
                num[2] += bf2f(u4.z); num[3] += bf2f(u4.w);
            }
            float rc = rden[r][h];
            ushort4 u = { f2bf(num[0] * rc), f2bf(num[1] * rc),
                          f2bf(num[2] * rc), f2bf(num[3] * rc) };
            *(ushort4*)&as_[r * 200 + c * 4] = u;
        }
    }
    __syncthreads();

    f32x4 acc[3];
#pragma unroll
    for (int j = 0; j < 3; ++j) acc[j] = (f32x4){0.f, 0.f, 0.f, 0.f};

    const unsigned short* wp = Wpb + (size_t)(wave * 48 + l16) * 192 + quad * 8;
#pragma unroll
    for (int ch = 0; ch < 6; ++ch) {
        bf16x8 a = *(const bf16x8*)&as_[l16 * 200 + ch * 32 + quad * 8];
#pragma unroll
        for (int jf = 0; jf < 3; ++jf) {
            bf16x8 bfr = *(const bf16x8*)(wp + (size_t)jf * 16 * 192 + ch * 32);
            acc[jf] = __builtin_amdgcn_mfma_f32_16x16x32_bf16(a, bfr, acc[jf], 0, 0, 0);
        }
    }

    const int m = m0 + quad * 4;
#pragma unroll
    for (int jf = 0; jf < 3; ++jf) {
        int n = wave * 48 + jf * 16 + l16;
        float bs = bproj[n];
#pragma unroll
        for (int i = 0; i < 4; ++i)
            out[(size_t)(m + i) * 192 + n] = acc[jf][i] + bs;
    }
}

// ---------------------------------------------------------------------------
extern "C" void kernel_launch(void* const* d_in, const int* in_sizes, int n_in,
                              void* d_out, int out_size, void* d_ws, size_t ws_size,
                              hipStream_t stream) {
    const float* x     = (const float*)d_in[0];
    const float* Wqkv  = (const float*)d_in[1];
    const float* bqkv  = (const float*)d_in[2];
    const float* Wproj = (const float*)d_in[3];
    const float* bproj = (const float*)d_in[4];
    float* out = (float*)d_out;

    // Workspace (~40 MB)
    unsigned short* Pnum = (unsigned short*)d_ws;            // 7*24*784*64 us (bf16)
    float* Pden = (float*)(Pnum + (size_t)KSPLIT * 24 * NQ * HD); // 7*24*784 f
    unsigned short* Qpb = (unsigned short*)(Pden + (size_t)KSPLIT * 24 * NQ);
    unsigned short* Kb  = Qpb + (size_t)24 * NQ * HD;        // 4,816,896 us
    unsigned short* Vt  = Kb + (size_t)BB * NK * DIMO;       // 4,816,896 us
    unsigned short* Wb  = Vt + (size_t)24 * HD * NK;         // 55,296 us
    unsigned short* Wpb = Wb + (size_t)576 * 96;             // 36,864 us

    // 1) weight prep
    wprep<<<24, 256, 0, stream>>>(Wqkv, Wproj, Wb, Wpb);

    // 2) fused qkv GEMM + Q-maxpool (batch-aligned XCD swizzle)
    qkv_fused<<<1008, 256, 0, stream>>>(x, Wb, bqkv, Qpb, Kb, Vt);

    // 3) MFMA attention partials (batch-per-XCD, L2-warm K/V)
    attn_mfma<<<1176, 256, 0, stream>>>(Qpb, Kb, Vt, Pnum, Pden);

    // 4) fused combine + proj (batch-per-XCD swizzle)
    proj_comb<<<392, 256, 0, stream>>>(Pnum, Pden, Wpb, bproj, out);
}